// Round 6
// baseline (204.426 us; speedup 1.0000x reference)
//
#include <hip/hip_runtime.h>

#define DIM    256
#define HALF   128
#define F0     10
#define F1     25
#define B0     1024
#define M1     10240            // B0 * F0
#define TASKS  (M1 + B0)        // 11264
#define NNODES 100000
#define NTILES (NNODES / 16)    // 6250
#define XBLK   625              // xform blocks; 6250/625 = 10 tiles each

typedef __attribute__((ext_vector_type(8))) short bf16x8;  // 8 bf16 = 4 VGPRs
typedef __attribute__((ext_vector_type(4))) float f32x4;

#define LSTRIDE 264   // LDS row stride in bf16 (528 B, 16B multiple)

__device__ __forceinline__ unsigned short f2bf(float x) {
    union { float f; unsigned u; } v; v.f = x;
    unsigned r = v.u + 0x7fffu + ((v.u >> 16) & 1u);   // RNE
    return (unsigned short)(r >> 16);
}
__device__ __forceinline__ float bf2f(unsigned short b) {
    union { unsigned u; float f; } v; v.u = ((unsigned)b) << 16;
    return v.f;
}
__device__ __forceinline__ unsigned packbf(float a, float b) {
    return (unsigned)f2bf(a) | ((unsigned)f2bf(b) << 16);
}

// ---------- Prep: W0_{self,neigh} -> bf16 B-fragments in frag-linear order.
// B-frag (tile t, kstep kk), lane = q*16+n, j=0..7 : W[kk*32+q*8+j][t*16+n]
__global__ __launch_bounds__(64) void prep_w(
    const float* __restrict__ Ws,
    const float* __restrict__ Wn,
    unsigned short* __restrict__ bfrag)
{
    const int bx   = blockIdx.x;       // [0,128)
    const int mat  = bx >> 6;
    const int f    = bx & 63;          // t*8+kk
    const int t    = f >> 3, kk = f & 7;
    const int lane = threadIdx.x;
    const int n    = lane & 15, q = lane >> 4;
    const float* W = mat ? Wn : Ws;

    __align__(16) unsigned short tmp[8];
    #pragma unroll
    for (int j = 0; j < 8; ++j)
        tmp[j] = f2bf(W[(kk * 32 + q * 8 + j) * HALF + t * 16 + n]);
    *(uint4*)(bfrag + ((size_t)(mat * 64 + f) * 64 + lane) * 8) = *(const uint4*)tmp;
}

// ---------- Xform: C_all[node][0:128] = feat@W0s, [128:256] = feat@W0n (bf16).
// Sequential full-BW pass over the feature table; B-fragments live in registers;
// double-buffered LDS A-tiles; 10 row-tiles per block.
__global__ __launch_bounds__(512, 2) void sage_xform(
    const float* __restrict__ feat,
    const unsigned short* __restrict__ bfrag,
    unsigned short* __restrict__ C_all)
{
    __shared__ __align__(16) unsigned short sh[2][16][LSTRIDE];

    const int tid  = threadIdx.x;
    const int wv   = __builtin_amdgcn_readfirstlane(tid >> 6);
    const int lane = tid & 63;
    const int h    = wv >> 2;          // 0: W0s half, 1: W0n half
    const int t0   = (wv & 3) * 2;     // col tiles t0, t0+1 within half
    const int m    = lane & 15;
    const int q    = lane >> 4;

    // register-resident B fragments: 2 tiles x 8 ksteps x 4 VGPRs = 64 VGPRs
    bf16x8 Bf0[8], Bf1[8];
    #pragma unroll
    for (int kk = 0; kk < 8; ++kk) {
        Bf0[kk] = *(const bf16x8*)(bfrag + ((size_t)(h * 64 + (t0 + 0) * 8 + kk) * 64 + lane) * 8);
        Bf1[kk] = *(const bf16x8*)(bfrag + ((size_t)(h * 64 + (t0 + 1) * 8 + kk) * 64 + lane) * 8);
    }

    // staging coords: 32 threads per row, 8 floats per thread
    const int sr = tid >> 5;           // 0..15
    const int sc = (tid & 31) * 8;     // 0..248

    int cur = blockIdx.x;
    float4 a, b;
    {
        const float* p = feat + ((size_t)cur * 16 + sr) * DIM + sc;
        a = *(const float4*)p; b = *(const float4*)(p + 4);
        unsigned u0 = packbf(a.x, a.y), u1 = packbf(a.z, a.w);
        unsigned u2 = packbf(b.x, b.y), u3 = packbf(b.z, b.w);
        *(uint2*)(&sh[0][sr][sc])     = make_uint2(u0, u1);
        *(uint2*)(&sh[0][sr][sc + 4]) = make_uint2(u2, u3);
    }

    for (int i = 0; i < 10; ++i) {
        float4 na, nb;
        if (i < 9) {
            const float* p = feat + ((size_t)(cur + XBLK) * 16 + sr) * DIM + sc;
            na = *(const float4*)p; nb = *(const float4*)(p + 4);
        }
        __syncthreads();               // buf[i&1] ready for all waves

        const int buf = i & 1;
        f32x4 acc0 = {0.f, 0.f, 0.f, 0.f};
        f32x4 acc1 = {0.f, 0.f, 0.f, 0.f};
        #pragma unroll
        for (int kk = 0; kk < 8; ++kk) {
            const bf16x8 af = *(const bf16x8*)(&sh[buf][m][kk * 32 + q * 8]);
            acc0 = __builtin_amdgcn_mfma_f32_16x16x32_bf16(af, Bf0[kk], acc0, 0, 0, 0);
            acc1 = __builtin_amdgcn_mfma_f32_16x16x32_bf16(af, Bf1[kk], acc1, 0, 0, 0);
        }
        #pragma unroll
        for (int reg = 0; reg < 4; ++reg) {
            const size_t row = (size_t)cur * 16 + q * 4 + reg;
            C_all[row * DIM + h * HALF + (t0 + 0) * 16 + m] = f2bf(acc0[reg]);
            C_all[row * DIM + h * HALF + (t0 + 1) * 16 + m] = f2bf(acc1[reg]);
        }

        if (i < 9) {
            unsigned u0 = packbf(na.x, na.y), u1 = packbf(na.z, na.w);
            unsigned u2 = packbf(nb.x, nb.y), u3 = packbf(nb.z, nb.w);
            *(uint2*)(&sh[buf ^ 1][sr][sc])     = make_uint2(u0, u1);
            *(uint2*)(&sh[buf ^ 1][sr][sc + 4]) = make_uint2(u2, u3);
        }
        cur += XBLK;
    }
}

// ---------- Gather: one wave per aggregate row, 256-byte half-row loads.
// Tasks [0, M1): n1[r] = relu(S[sn1 r]) || relu(mean25 G[sn2..])  -> bf16
// Tasks [M1, TASKS): n0[r] = relu(S[sn0 r]) || relu(mean10 G[sn1..]) -> fp32 (d_out)
__global__ __launch_bounds__(256, 8) void sage_gather(
    const unsigned short* __restrict__ C_all,
    const int* __restrict__ sn0,
    const int* __restrict__ sn1,
    const int* __restrict__ sn2,
    unsigned short* __restrict__ n1,
    float*          __restrict__ n0)
{
    const int wv   = __builtin_amdgcn_readfirstlane(threadIdx.x >> 6);
    const int lane = threadIdx.x & 63;
    const int task = blockIdx.x * 4 + wv;
    const unsigned* C = (const unsigned*)C_all;     // 128 uints per node row

    if (task < M1) {
        const int si = sn1[task];                    // wave-uniform scalar
        const unsigned su = C[(size_t)si * 128 + lane];           // S half
        const float s0 = fmaxf(bf2f((unsigned short)(su & 0xffff)), 0.f);
        const float s1 = fmaxf(bf2f((unsigned short)(su >> 16)),   0.f);

        float a0 = 0.f, a1 = 0.f;
        #pragma unroll
        for (int j = 0; j < F1; ++j) {
            const int gi = sn2[task * F1 + j];       // wave-uniform scalar
            const unsigned g = C[(size_t)gi * 128 + 64 + lane];   // G half
            a0 += bf2f((unsigned short)(g & 0xffff));
            a1 += bf2f((unsigned short)(g >> 16));
        }
        const float sc = 1.0f / (float)F1;
        a0 = fmaxf(a0 * sc, 0.f); a1 = fmaxf(a1 * sc, 0.f);

        unsigned* dst = (unsigned*)(n1 + (size_t)task * DIM);
        dst[lane]      = packbf(s0, s1);
        dst[64 + lane] = packbf(a0, a1);
    } else {
        const int r  = task - M1;
        const int si = sn0[r];
        const unsigned su = C[(size_t)si * 128 + lane];
        const float s0 = fmaxf(bf2f((unsigned short)(su & 0xffff)), 0.f);
        const float s1 = fmaxf(bf2f((unsigned short)(su >> 16)),   0.f);

        float a0 = 0.f, a1 = 0.f;
        #pragma unroll
        for (int j = 0; j < F0; ++j) {
            const int gi = sn1[r * F0 + j];
            const unsigned g = C[(size_t)gi * 128 + 64 + lane];
            a0 += bf2f((unsigned short)(g & 0xffff));
            a1 += bf2f((unsigned short)(g >> 16));
        }
        const float sc = 1.0f / (float)F0;
        a0 = fmaxf(a0 * sc, 0.f); a1 = fmaxf(a1 * sc, 0.f);

        float2 s2; s2.x = s0; s2.y = s1;
        float2 a2; a2.x = a0; a2.y = a1;
        *(float2*)(n0 + (size_t)r * DIM + 2 * lane)        = s2;
        *(float2*)(n0 + (size_t)r * DIM + HALF + 2 * lane) = a2;
    }
}

// ---------- Final layer: out = concat(n0 @ W1s, mean10(n1) @ W1n), fp32 VALU.
#define PAD 260
#define R2  4

__global__ __launch_bounds__(256) void sage_final(
    const unsigned short* __restrict__ n1,
    const float* __restrict__ W1s,
    const float* __restrict__ W1n,
    float*       out)              // aliases n0 input — no restrict
{
    __shared__ float sh_n0 [R2][PAD];
    __shared__ float sh_agg[R2][PAD];

    const int tid     = threadIdx.x;
    const int rowbase = blockIdx.x * R2;
    const int wave    = tid >> 6;
    const int lane    = tid & 63;

    {
        const int r = wave;
        *(float4*)(&sh_n0[r][lane * 4]) =
            *(const float4*)(out + (size_t)(rowbase + r) * DIM + lane * 4);

        const unsigned short* base = n1 + ((size_t)(rowbase + r) * F0) * DIM + lane * 4;
        float4 a = make_float4(0.f, 0.f, 0.f, 0.f);
        #pragma unroll
        for (int j = 0; j < F0; ++j) {
            const uint2 p = *(const uint2*)(base + (size_t)j * DIM);
            a.x += bf2f((unsigned short)(p.x & 0xffff));
            a.y += bf2f((unsigned short)(p.x >> 16));
            a.z += bf2f((unsigned short)(p.y & 0xffff));
            a.w += bf2f((unsigned short)(p.y >> 16));
        }
        const float sc = 1.0f / (float)F0;
        a.x *= sc; a.y *= sc; a.z *= sc; a.w *= sc;
        *(float4*)(&sh_agg[r][lane * 4]) = a;
    }
    __syncthreads();

    const int  u     = tid & 127;
    const int  c0    = u * 2;
    const int  rb    = (tid >> 7) * 2;
    const bool neigh = (c0 >= HALF);
    const float* __restrict__ W = neigh ? W1n : W1s;
    const int  col   = neigh ? (c0 - HALF) : c0;
    const float (*src)[PAD] = neigh ? sh_agg : sh_n0;

    float a0[2] = {0.f, 0.f}, a1[2] = {0.f, 0.f};
    for (int d = 0; d < DIM; d += 4) {
        const float2 w0 = *(const float2*)(W + (d + 0) * HALF + col);
        const float2 w1 = *(const float2*)(W + (d + 1) * HALF + col);
        const float2 w2 = *(const float2*)(W + (d + 2) * HALF + col);
        const float2 w3 = *(const float2*)(W + (d + 3) * HALF + col);
        #pragma unroll
        for (int r = 0; r < 2; ++r) {
            const float4 hh = *(const float4*)(&src[rb + r][d]);
            a0[r] += hh.x * w0.x + hh.y * w1.x + hh.z * w2.x + hh.w * w3.x;
            a1[r] += hh.x * w0.y + hh.y * w1.y + hh.z * w2.y + hh.w * w3.y;
        }
    }

    #pragma unroll
    for (int r = 0; r < 2; ++r) {
        float2 o;
        o.x = a0[r];
        o.y = a1[r];
        *(float2*)(out + (size_t)(rowbase + rb + r) * DIM + c0) = o;
    }
}

extern "C" void kernel_launch(void* const* d_in, const int* in_sizes, int n_in,
                              void* d_out, int out_size, void* d_ws, size_t ws_size,
                              hipStream_t stream) {
    (void)in_sizes; (void)n_in; (void)out_size; (void)ws_size;
    const float* feat = (const float*)d_in[0];
    const int*   sn0  = (const int*)  d_in[1];
    const int*   sn1  = (const int*)  d_in[2];
    const int*   sn2  = (const int*)  d_in[3];
    const float* W0s  = (const float*)d_in[4];
    const float* W0n  = (const float*)d_in[5];
    const float* W1s  = (const float*)d_in[6];
    const float* W1n  = (const float*)d_in[7];
    float* out = (float*)d_out;

    // ws layout (16B-aligned):
    //   [0, 5 MB)        n1 bf16            10240*256*2 = 5,242,880
    //   [+, 51.2 MB)     C_all bf16         100000*256*2 = 51,200,000
    //   [+, 128 KB)      W0 B-fragments     131,072
    unsigned short* n1    = (unsigned short*)d_ws;
    unsigned short* C_all = (unsigned short*)((char*)d_ws + 5242880);
    unsigned short* bfrag = (unsigned short*)((char*)d_ws + 5242880 + 51200000);

    prep_w     <<<128, 64, 0, stream>>>(W0s, W0n, bfrag);
    sage_xform <<<XBLK, 512, 0, stream>>>(feat, bfrag, C_all);
    // n0 (1024x256 fp32) staged in d_out, then overwritten in-place by sage_final.
    sage_gather<<<TASKS / 4, 256, 0, stream>>>(C_all, sn0, sn1, sn2, n1, out);
    sage_final <<<B0 / R2, 256, 0, stream>>>(n1, W1s, W1n, out);
}